// Round 8
// baseline (95.230 us; speedup 1.0000x reference)
//
#include <hip/hip_runtime.h>
#include <math.h>

// Problem dims (fixed by setup_inputs): n=32, t=8, c=128, h=w=32
#define TC  1024   // t*c channels
#define P_  1024   // h*w pixels
#define KC  64     // int(c*0.5)
#define KT  4      // int(t*0.5)

typedef float vfloat4 __attribute__((ext_vector_type(4)));   // native vec for NT store

// workspace layout (float offsets):
//   avg    [0,      32768)    per (n,t,c) spatial mean
//   mx     [32768,  65536)    per (n,t,c) spatial max
//   mask_c [65536,  66560)    int, batch-union channel-topk mask
//   mask_t [66560,  67584)    int, batch-union time-topk mask
//   flag   [67584,  68608)    float XOR mask (im=1)
//   im_map [68608,  101376)   [n][pix]
//   sub_map[101376, 134144)   [n][pix]
//   part   [134144, 658432)   [cq=4][n=32][stat=4][pix=1024] pooled partials

// ---------- K1: spatial mean/max, two rows per wave --------------------------
// 4096 blocks x 256 thr = 4 waves; wave w handles rows blockIdx*8 + w*2 (+1).
// 8 float4 loads in flight per wave, two independent shfl-reduce chains,
// float2 result stores. Block 0 also zeros the masks (2048 ints).
__global__ __launch_bounds__(256) void k1_reduce(const float* __restrict__ x,
                                                 float* __restrict__ avg,
                                                 float* __restrict__ mx,
                                                 int* __restrict__ masks) {
    if (blockIdx.x == 0) {
        for (int j = threadIdx.x; j < 2048; j += 256) masks[j] = 0;
    }
    int wid = threadIdx.x >> 6, lane = threadIdx.x & 63;
    int r0 = blockIdx.x * 8 + wid * 2;        // even row index
    const float4* xp0 = (const float4*)(x + (size_t)r0 * P_) + lane;
    const float4* xp1 = xp0 + 256;            // next row
    float4 a0 = xp0[0], b0 = xp0[64], c0 = xp0[128], d0 = xp0[192];
    float4 a1 = xp1[0], b1 = xp1[64], c1 = xp1[128], d1 = xp1[192];
    float s0 = ((a0.x + a0.y) + (a0.z + a0.w)) + ((b0.x + b0.y) + (b0.z + b0.w))
             + ((c0.x + c0.y) + (c0.z + c0.w)) + ((d0.x + d0.y) + (d0.z + d0.w));
    float m0 = fmaxf(fmaxf(fmaxf(fmaxf(a0.x, a0.y), fmaxf(a0.z, a0.w)),
                           fmaxf(fmaxf(b0.x, b0.y), fmaxf(b0.z, b0.w))),
                     fmaxf(fmaxf(fmaxf(c0.x, c0.y), fmaxf(c0.z, c0.w)),
                           fmaxf(fmaxf(d0.x, d0.y), fmaxf(d0.z, d0.w))));
    float s1 = ((a1.x + a1.y) + (a1.z + a1.w)) + ((b1.x + b1.y) + (b1.z + b1.w))
             + ((c1.x + c1.y) + (c1.z + c1.w)) + ((d1.x + d1.y) + (d1.z + d1.w));
    float m1 = fmaxf(fmaxf(fmaxf(fmaxf(a1.x, a1.y), fmaxf(a1.z, a1.w)),
                           fmaxf(fmaxf(b1.x, b1.y), fmaxf(b1.z, b1.w))),
                     fmaxf(fmaxf(fmaxf(c1.x, c1.y), fmaxf(c1.z, c1.w)),
                           fmaxf(fmaxf(d1.x, d1.y), fmaxf(d1.z, d1.w))));
    #pragma unroll
    for (int off = 32; off > 0; off >>= 1) {
        s0 += __shfl_down(s0, off);
        m0  = fmaxf(m0, __shfl_down(m0, off));
        s1 += __shfl_down(s1, off);
        m1  = fmaxf(m1, __shfl_down(m1, off));
    }
    if (lane == 0) {
        float2 av = {s0 * (1.0f / 1024.0f), s1 * (1.0f / 1024.0f)};
        float2 mv = {m0, m1};
        *(float2*)(avg + r0) = av;
        *(float2*)(mx  + r0) = mv;
    }
}

// ---------- K2: map_add + fc + exact top-k rank masks; block = (n, tt) -------
__global__ __launch_bounds__(256) void k2_map(const float* __restrict__ avg,
                                              const float* __restrict__ mx,
                                              const float* __restrict__ alpha,
                                              const float* __restrict__ beta,
                                              const float* __restrict__ wfc,
                                              int* __restrict__ mask_c,
                                              int* __restrict__ mask_t) {
    __shared__ float m[TC], mf[TC], w[64];
    int n = blockIdx.x >> 3, tt = blockIdx.x & 7;
    float a0 = alpha[0], b0 = beta[0];
    if (threadIdx.x < 64) w[threadIdx.x] = wfc[threadIdx.x];
    for (int i = threadIdx.x; i < TC; i += 256) {
        float a = avg[n * TC + i], b = mx[n * TC + i];
        m[i] = 0.5f * (a + b) + a0 * a + b0 * b;
    }
    __syncthreads();
    // fc along time: mf[s*128+c] = sum_t m[t*128+c] * W[s][t]
    for (int i = threadIdx.x; i < TC; i += 256) {
        int s = i >> 7, cc = i & 127;
        float acc = 0.0f;
        #pragma unroll
        for (int t2 = 0; t2 < 8; ++t2) acc += m[t2 * 128 + cc] * w[s * 8 + t2];
        mf[i] = acc;
    }
    __syncthreads();
    // exact lax.top_k emulation for row tt: selected iff
    //   #{j: v_j > v_i} + #{j: v_j == v_i && j < i} < k
    if (threadIdx.x < 128) {
        int cc = threadIdx.x, i = tt * 128 + cc;
        float v = mf[i];
        int rc = 0;
        #pragma unroll 16
        for (int c2 = 0; c2 < 128; ++c2) {
            float u = mf[tt * 128 + c2];
            rc += (u > v) || (u == v && c2 < cc);
        }
        if (rc < KC) mask_c[i] = 1;   // benign race: all writers store 1
        int rt = 0;
        #pragma unroll
        for (int t2 = 0; t2 < 8; ++t2) {
            float u = mf[t2 * 128 + cc];
            rt += (u > v) || (u == v && t2 < tt);
        }
        if (rt < KT) mask_t[i] = 1;
    }
}

// ---------- K4: masked channel stats; block = (n, pix-quarter, chan-quarter) --
// 512 blocks x 256 thr. Thread (cg = tid>>6, l = tid&63) accumulates 64
// channels for float4-pixel pq*64+l; LDS-reduce across the 4 cg subgroups;
// write pooled partials [cq][n][stat][pix].
__global__ __launch_bounds__(256) void k4_partial(const float* __restrict__ x,
                                                  const int* __restrict__ mask_c,
                                                  const int* __restrict__ mask_t,
                                                  float* __restrict__ flag_out,
                                                  float* __restrict__ part) {
    int b = blockIdx.x;
    int cq = b & 3, pq = (b >> 2) & 3, n = b >> 4;
    __shared__ float sf[256];
    __shared__ float4 red[4][4][64];   // [stat][cg][l]
    {
        int i = threadIdx.x;
        int ch = cq * 256 + i;
        float f = ((mask_c[ch] != 0) != (mask_t[ch] != 0)) ? 1.0f : 0.0f;
        sf[i] = f;
        if (n == 0 && pq == 0) flag_out[ch] = f;
    }
    __syncthreads();
    int l = threadIdx.x & 63, cg = threadIdx.x >> 6;
    int f4p = pq * 64 + l;
    int ch0 = cq * 256 + cg * 64;
    const float4* xb = (const float4*)x + ((size_t)(n * TC + ch0)) * 256 + f4p;
    float4 ims  = {0.f, 0.f, 0.f, 0.f};
    float4 subs = {0.f, 0.f, 0.f, 0.f};
    float4 imm  = {-INFINITY, -INFINITY, -INFINITY, -INFINITY};
    float4 subm = {-INFINITY, -INFINITY, -INFINITY, -INFINITY};
    #pragma unroll 8
    for (int k = 0; k < 64; ++k) {
        float4 v = xb[(size_t)k * 256];
        float f = sf[cg * 64 + k];
        float iv;
        iv = v.x * f; ims.x += iv; imm.x = fmaxf(imm.x, iv);
        v.x -= iv;    subs.x += v.x; subm.x = fmaxf(subm.x, v.x);
        iv = v.y * f; ims.y += iv; imm.y = fmaxf(imm.y, iv);
        v.y -= iv;    subs.y += v.y; subm.y = fmaxf(subm.y, v.y);
        iv = v.z * f; ims.z += iv; imm.z = fmaxf(imm.z, iv);
        v.z -= iv;    subs.z += v.z; subm.z = fmaxf(subm.z, v.z);
        iv = v.w * f; ims.w += iv; imm.w = fmaxf(imm.w, iv);
        v.w -= iv;    subs.w += v.w; subm.w = fmaxf(subm.w, v.w);
    }
    red[0][cg][l] = ims;
    red[1][cg][l] = imm;
    red[2][cg][l] = subs;
    red[3][cg][l] = subm;
    __syncthreads();
    if (threadIdx.x < 64) {
        float4 s0 = red[0][0][l], s1 = red[1][0][l], s2 = red[2][0][l], s3 = red[3][0][l];
        #pragma unroll
        for (int g = 1; g < 4; ++g) {
            float4 a = red[0][g][l], bq = red[1][g][l], c = red[2][g][l], d = red[3][g][l];
            s0.x += a.x; s0.y += a.y; s0.z += a.z; s0.w += a.w;
            s1.x = fmaxf(s1.x, bq.x); s1.y = fmaxf(s1.y, bq.y);
            s1.z = fmaxf(s1.z, bq.z); s1.w = fmaxf(s1.w, bq.w);
            s2.x += c.x; s2.y += c.y; s2.z += c.z; s2.w += c.w;
            s3.x = fmaxf(s3.x, d.x); s3.y = fmaxf(s3.y, d.y);
            s3.z = fmaxf(s3.z, d.z); s3.w = fmaxf(s3.w, d.w);
        }
        float4* pp = (float4*)part + ((size_t)(cq * 32 + n) * 4) * 256 + f4p;
        pp[0]   = s0;
        pp[256] = s1;
        pp[512] = s2;
        pp[768] = s3;
    }
}

// ---------- K5: combine 4 chan-quarters -> pooled (LDS) -> 3x3 conv + sigmoid -
__global__ __launch_bounds__(1024) void k5_conv(const float* __restrict__ part,
                                                const float* __restrict__ w1,
                                                const float* __restrict__ w2,
                                                float* __restrict__ im_map,
                                                float* __restrict__ sub_map) {
    __shared__ float sp[4][P_];
    int n = blockIdx.x, p = threadIdx.x;
    float s_im = 0.f, s_sub = 0.f, m_im = -INFINITY, m_sub = -INFINITY;
    #pragma unroll
    for (int q = 0; q < 4; ++q) {
        size_t base = ((size_t)(q * 32 + n) * 4) * P_ + p;
        s_im  += part[base];
        m_im   = fmaxf(m_im, part[base + 1024]);
        s_sub += part[base + 2048];
        m_sub  = fmaxf(m_sub, part[base + 3072]);
    }
    sp[0][p] = s_im  * (2.0f / 1024.0f);   // mean / LAM
    sp[1][p] = m_im;
    sp[2][p] = s_sub * (2.0f / 1024.0f);   // mean / (1-LAM)
    sp[3][p] = m_sub;
    __syncthreads();
    int y = p >> 5, xx = p & 31;
    float acc1 = 0.0f, acc2 = 0.0f;
    #pragma unroll
    for (int i = 0; i < 2; ++i)
        #pragma unroll
        for (int dy = 0; dy < 3; ++dy) {
            int yy = y + dy - 1;
            if (yy < 0 || yy >= 32) continue;
            #pragma unroll
            for (int dx = 0; dx < 3; ++dx) {
                int xc = xx + dx - 1;
                if (xc < 0 || xc >= 32) continue;
                acc1 += sp[i][yy * 32 + xc]     * w1[i * 9 + dy * 3 + dx];
                acc2 += sp[2 + i][yy * 32 + xc] * w2[i * 9 + dy * 3 + dx];
            }
        }
    im_map[n * P_ + p]  = 1.0f / (1.0f + expf(-acc1));
    sub_map[n * P_ + p] = 1.0f / (1.0f + expf(-acc2));
}

// ---------- K6: out = x * (flag ? im_map : sub_map); grid-stride, NT stores ---
// 2048 blocks; thread base tid0 handles 4 groups at stride 524288; each group
// g -> n = g>>16, rem = g&65535 (ch = rem>>8, pixf4 = rem&255) and 4 j-steps
// of +256 channels (65536 float4) within the same n. Full coverage of all
// 2^23 float4, map vectors hoisted per group, flag loads wave-uniform.
__global__ __launch_bounds__(256) void k6_out(const float* __restrict__ x,
                                              const float* __restrict__ flag,
                                              const float* __restrict__ im_map,
                                              const float* __restrict__ sub_map,
                                              float* __restrict__ out) {
    int tid0 = blockIdx.x * 256 + threadIdx.x;      // 0 .. 524287
    #pragma unroll
    for (int kk = 0; kk < 4; ++kk) {
        int g   = tid0 + kk * 524288;               // 0 .. 2097151
        int n   = g >> 16;
        int rem = g & 65535;
        int ch    = rem >> 8;                       // 0..255 (channel row base)
        int pixf4 = rem & 255;
        size_t base = ((size_t)n << 18) + rem;      // float4 index
        const float4* xp = (const float4*)x + base;
        float4 im_v  = ((const float4*)im_map )[n * 256 + pixf4];
        float4 sub_v = ((const float4*)sub_map)[n * 256 + pixf4];
        #pragma unroll
        for (int j = 0; j < 4; ++j) {
            float4 xv = xp[j * 65536];              // +256 channels, same pixel
            bool im = flag[ch + j * 256] != 0.0f;
            float4 mv = im ? im_v : sub_v;
            vfloat4 o;
            o.x = xv.x * mv.x; o.y = xv.y * mv.y; o.z = xv.z * mv.z; o.w = xv.w * mv.w;
            __builtin_nontemporal_store(o, (vfloat4*)out + base + (size_t)j * 65536);
        }
    }
}

extern "C" void kernel_launch(void* const* d_in, const int* in_sizes, int n_in,
                              void* d_out, int out_size, void* d_ws, size_t ws_size,
                              hipStream_t stream) {
    const float* x     = (const float*)d_in[0];
    const float* alpha = (const float*)d_in[1];
    const float* beta  = (const float*)d_in[2];
    const float* wfc   = (const float*)d_in[3];
    const float* w1    = (const float*)d_in[4];
    const float* w2    = (const float*)d_in[5];
    float* out = (float*)d_out;
    float* ws  = (float*)d_ws;

    float* avg     = ws;
    float* mx      = ws + 32768;
    int*   mask_c  = (int*)(ws + 65536);   // mask_t contiguous after it
    int*   mask_t  = (int*)(ws + 66560);
    float* flag    = ws + 67584;
    float* im_map  = ws + 68608;
    float* sub_map = ws + 101376;
    float* part    = ws + 134144;

    k1_reduce <<<4096,  256, 0, stream>>>(x, avg, mx, mask_c);  // zeros masks
    k2_map    <<<256,   256, 0, stream>>>(avg, mx, alpha, beta, wfc, mask_c, mask_t);
    k4_partial<<<512,   256, 0, stream>>>(x, mask_c, mask_t, flag, part);
    k5_conv   <<<32,   1024, 0, stream>>>(part, w1, w2, im_map, sub_map);
    k6_out    <<<2048,  256, 0, stream>>>(x, flag, im_map, sub_map, out);
}